// Round 7
// baseline (82.288 us; speedup 1.0000x reference)
//
#include <hip/hip_runtime.h>

#define NB 8
#define NT 400
#define NN 200
#define ND 80
#define NTP ((NT - 1) / 2)   // 199 double-step pairs: t1=2tp+1, t2=2tp+2

static constexpr float BIG_NEG = -1e30f;
static constexpr float LN2 = 0.6931471805599453f;
static constexpr float LOG2E = 1.4426950408889634f;
static constexpr float L2EPS = -99.65784284662087f;        // log(1e-30)*LOG2E
static constexpr float HALF_LOG2E = 0.7213475204444817f;   // 0.5*LOG2E
static constexpr float D_HALF_L2PI = 106.05984517680935f;  // D*0.5*log2(2pi)

static __device__ __forceinline__ float hw_exp2(float x) { return __builtin_amdgcn_exp2f(x); }
static __device__ __forceinline__ float hw_log2(float x) { return __builtin_amdgcn_logf(x); }

// exact log2(2^a + 2^b) (2 trans ops) -- used OUTSIDE the serial loop
static __device__ __forceinline__ float l2add(float a, float b) {
    float mx = fmaxf(a, b);
    float d = fminf(a, b) - mx;  // <= 0
    return mx + hw_log2(1.0f + hw_exp2(d));
}

// fast log2(2^a + 2^b): 1 trans + cubic for log2(1+u), u in [0,1].
// Exact at u=0 and u=1; max err ~ +0.011 log2-units (one l2add per state per
// t-step on the serial path -> <= ~5 abs on output vs threshold 1162).
static __device__ __forceinline__ float pl2add(float x, float y) {
    float mx = fmaxf(x, y);
    float d = fminf(x, y) - mx;            // <= 0
    float u = hw_exp2(d);                  // 2^d in [0,1]
    float p = fmaf(0.1177f, u, -0.5604f);
    p = fmaf(p, u, 1.4427f);
    return fmaf(u, p, mx);                 // mx + log2(1+u) approx
}

// log2(1 + 2^-|w|), in [0,1] (exact; used only in parallel kernels)
static __device__ __forceinline__ float softplus2(float w) {
    return hw_log2(1.0f + hw_exp2(-fabsf(w)));
}

// whole-wave shift right by 1 lane via DPP; lane 0 receives `fill`
static __device__ __forceinline__ float wave_shr1(float x, float fill) {
    int r = __builtin_amdgcn_update_dpp(__float_as_int(fill), __float_as_int(x),
                                        0x138 /*wave_shr:1*/, 0xF, 0xF, false);
    return __int_as_float(r);
}

// ---------------------------------------------------------------------------
// Kernel 1 (log2 domain): e2 = LOG2E * emission.
//   SE[t][n] = e2 + log2(sigmoid(-tv[t][n]))      (stay)
//   ME[t][n] = e2 + log2(sigmoid( tv[t][n-1]))    (move, pre-shifted)
// ---------------------------------------------------------------------------
__global__ __launch_bounds__(256) void emission_kernel(
    const float* __restrict__ mels,   // (B,T,D)
    const float* __restrict__ means,  // (B,T,N,D)
    const float* __restrict__ stds,   // (B,T,N,D)
    const float* __restrict__ tv,     // (B,T,N)
    const int* __restrict__ inputs_len,
    const int* __restrict__ mel_lens,
    float* __restrict__ SE,           // (B,T,N) workspace
    float* __restrict__ ME)           // (B,T,N) workspace
{
    const int tid = threadIdx.x;
    const int R = blockIdx.x * 64 + (tid >> 2);  // row in [0, B*T*N)
    const int q = tid & 3;
    const int b = R / (NT * NN);
    const int r2 = R - b * (NT * NN);
    const int t = r2 / NN;
    const int n = r2 - t * NN;

    if (t >= mel_lens[b]) return;
    if (n >= inputs_len[b]) {
        if (q == 0) { SE[R] = BIG_NEG; ME[R] = BIG_NEG; }
        return;
    }

    const float4* mp = reinterpret_cast<const float4*>(means) + (size_t)R * (ND / 4) + q;
    const float4* sp = reinterpret_cast<const float4*>(stds)  + (size_t)R * (ND / 4) + q;
    const float4* xp = reinterpret_cast<const float4*>(mels)  + (size_t)(b * NT + t) * (ND / 4) + q;

    float acc = 0.f;    // sum z^2
    float prod = 1.f;   // prod of stds (20 values in [9.5e-7, 3325]: safe)
#pragma unroll
    for (int k = 0; k < ND / 16; ++k) {
        const float4 m = mp[k * 4];
        const float4 s = sp[k * 4];
        const float4 x = xp[k * 4];
        float z0 = __fdividef(x.x - m.x, s.x);
        float z1 = __fdividef(x.y - m.y, s.y);
        float z2 = __fdividef(x.z - m.z, s.z);
        float z3 = __fdividef(x.w - m.w, s.w);
        acc = fmaf(z0, z0, acc);
        acc = fmaf(z1, z1, acc);
        acc = fmaf(z2, z2, acc);
        acc = fmaf(z3, z3, acc);
        prod *= s.x * s.y * s.z * s.w;
    }
    acc = fmaf(acc, HALF_LOG2E, hw_log2(prod));  // HALF_LOG2E*sum(z^2)+log2(prod s)
    acc += __shfl_xor(acc, 1);
    acc += __shfl_xor(acc, 2);

    if (q == 0) {
        const float e2 = -acc - D_HALF_L2PI;
        if (t == 0) {
            SE[R] = e2;              // raw (log2-scaled) emission; only n==0 used
            ME[R] = BIG_NEG;
        } else {
            const size_t base = (size_t)b * NT * NN + (size_t)t * NN;
            float w = tv[base + n] * LOG2E;
            float stay2 = -(fmaxf(w, 0.f) + softplus2(w));     // log2 sigmoid(-v)
            SE[R] = e2 + fmaxf(stay2, L2EPS);
            if (n == 0) {
                ME[R] = BIG_NEG;
            } else {
                float u = tv[base + n - 1] * LOG2E;
                float mv2 = -(fmaxf(-u, 0.f) + softplus2(u));  // log2 sigmoid(v)
                ME[R] = e2 + fmaxf(mv2, L2EPS);
            }
        }
    }
}

// ---------------------------------------------------------------------------
// Kernel 2: build double-step arrays for pairs (t1,t2)=(2tp+1, 2tp+2):
//   A2[n] = SE[t1][n] + SE[t2][n]                        (stay,stay)
//   B2[n] = lse(ME[t1][n]+SE[t2][n], SE[t1][n-1]+ME[t2][n])  (one shift)
//   C2[n] = ME[t1][n-1] + ME[t2][n]                      (two shifts)
// Rows with t >= mel_lens hold stale poison; their combines are never read.
// ---------------------------------------------------------------------------
__global__ __launch_bounds__(256) void combine_kernel(
    const float* __restrict__ SE, const float* __restrict__ ME,
    float* __restrict__ A2, float* __restrict__ B2, float* __restrict__ C2)
{
    const int idx = blockIdx.x * 256 + threadIdx.x;
    if (idx >= NB * NTP * NN) return;
    const int b = idx / (NTP * NN);
    const int r = idx - b * (NTP * NN);
    const int tp = r / NN;
    const int n = r - tp * NN;
    const size_t o1 = (size_t)b * NT * NN + (size_t)(2 * tp + 1) * NN + n;
    const size_t o2 = o1 + NN;
    const float se1 = SE[o1], se2 = SE[o2];
    const float me1 = ME[o1], me2 = ME[o2];
    const float se1m = (n > 0) ? SE[o1 - 1] : BIG_NEG;
    const float me1m = (n > 0) ? ME[o1 - 1] : BIG_NEG;
    A2[idx] = se1 + se2;
    B2[idx] = l2add(me1 + se2, se1m + me2);
    C2[idx] = me1m + me2;
}

// ---------------------------------------------------------------------------
// Kernel 3: forward recursion, TWO t-steps per iteration:
//   la[n] <- lse3(la[n]+A2[n], la[n-1]+B2[n], la[n-2]+C2[n])
// One wave per b; lane l holds states 4l..4l+3; 2 DPP shifts per double-step.
// Depth-8 slot pipeline (static names). Tail: <=7 pairs + optional single
// step at t=ml-1 (iff ml even) using SE/ME directly.
// ---------------------------------------------------------------------------
__global__ __launch_bounds__(64) void scan_kernel(
    const float* __restrict__ SE, const float* __restrict__ ME,
    const float* __restrict__ A2, const float* __restrict__ B2,
    const float* __restrict__ C2, const float* __restrict__ tv,
    const int* __restrict__ inputs_len, const int* __restrict__ mel_lens,
    float* __restrict__ out)
{
    const int b = blockIdx.x;
    const int lane = threadIdx.x;
    const int il = inputs_len[b];
    const int ml = mel_lens[b];
    const int mlm1 = ml - 1;
    const int P = (ml - 1) / 2;   // pairs cover t = 1..2P; P >= 99
    const int cl = (lane < NN / 4) ? lane : (NN / 4 - 1);

    const float* seb = SE + (size_t)b * NT * NN;
    const float* meb = ME + (size_t)b * NT * NN;
    const float* a2b = A2 + (size_t)b * NTP * NN;
    const float* b2b = B2 + (size_t)b * NTP * NN;
    const float* c2b = C2 + (size_t)b * NTP * NN;
    const float* vb  = tv + (size_t)b * NT * NN;

    float la0 = (lane == 0) ? seb[0] : BIG_NEG;
    float la1 = BIG_NEG, la2 = BIG_NEG, la3 = BIG_NEG;

    auto ld4 = [cl](const float* p) { return reinterpret_cast<const float4*>(p)[cl]; };
#define LDP(TT) ((size_t)(((TT) < P) ? (TT) : (P - 1)) * NN)

#define PREL(S, TT) \
    float4 pa##S = ld4(a2b + LDP(TT)); \
    float4 pb##S = ld4(b2b + LDP(TT)); \
    float4 pc##S = ld4(c2b + LDP(TT));
    PREL(0, 0) PREL(1, 1) PREL(2, 2) PREL(3, 3)
    PREL(4, 4) PREL(5, 5) PREL(6, 6) PREL(7, 7)
#undef PREL

#define DBODY(AV, BV, CV) { \
        float p3 = wave_shr1(la3, BIG_NEG); \
        float p2 = wave_shr1(la2, BIG_NEG); \
        float t0 = pl2add(la0 + AV.x, p3 + BV.x);  t0 = pl2add(t0, p2 + CV.x); \
        float t1 = pl2add(la1 + AV.y, la0 + BV.y); t1 = pl2add(t1, p3 + CV.y); \
        float t2 = pl2add(la2 + AV.z, la1 + BV.z); t2 = pl2add(t2, la0 + CV.z); \
        float t3 = pl2add(la3 + AV.w, la2 + BV.w); t3 = pl2add(t3, la1 + CV.w); \
        la0 = t0; la1 = t1; la2 = t2; la3 = t3; }

#define DSTEP(S, TT) { \
        float4 A_ = pa##S, B_ = pb##S, C_ = pc##S; \
        pa##S = ld4(a2b + LDP((TT) + 8)); \
        pb##S = ld4(b2b + LDP((TT) + 8)); \
        pc##S = ld4(c2b + LDP((TT) + 8)); \
        DBODY(A_, B_, C_) }

#define TDSTEP(S) if (tp + (S) < P) { DBODY(pa##S, pb##S, pc##S) }

    int tp = 0;
    for (; tp + 7 < P; tp += 8) {
        DSTEP(0, tp)     DSTEP(1, tp + 1) DSTEP(2, tp + 2) DSTEP(3, tp + 3)
        DSTEP(4, tp + 4) DSTEP(5, tp + 5) DSTEP(6, tp + 6) DSTEP(7, tp + 7)
    }
    // tail pairs (<=7): slots S hold pair tp+S
    TDSTEP(0) TDSTEP(1) TDSTEP(2) TDSTEP(3) TDSTEP(4) TDSTEP(5) TDSTEP(6)
#undef DSTEP
#undef TDSTEP
#undef DBODY
#undef LDP

    // leftover single step at t = ml-1 iff ml is even (exact l2add, once)
    if ((ml & 1) == 0) {
        float4 se = ld4(seb + (size_t)mlm1 * NN);
        float4 me = ld4(meb + (size_t)mlm1 * NN);
        float carry = wave_shr1(la3, BIG_NEG);
        float a0 = la0 + se.x, c0 = carry + me.x;
        float a1 = la1 + se.y, c1 = la0 + me.y;
        float a2 = la2 + se.z, c2 = la1 + me.z;
        float a3 = la3 + se.w, c3 = la2 + me.w;
        la0 = l2add(a0, c0);
        la1 = l2add(a1, c1);
        la2 = l2add(a2, c2);
        la3 = l2add(a3, c3);
    }

    // final: only state il-1 contributes
    const int fin = il - 1;
    const int n0 = lane * 4;
    if (fin >= n0 && fin < n0 + 4) {
        float w = vb[(size_t)mlm1 * NN + fin] * LOG2E;
        float lmove2 = fmaxf(-(fmaxf(-w, 0.f) + softplus2(w)), L2EPS);
        float lastla = (fin == n0)     ? la0
                     : (fin == n0 + 1) ? la1
                     : (fin == n0 + 2) ? la2
                                       : la3;
        out[b] = LN2 * (lastla + lmove2);
    }
}

extern "C" void kernel_launch(void* const* d_in, const int* in_sizes, int n_in,
                              void* d_out, int out_size, void* d_ws, size_t ws_size,
                              hipStream_t stream) {
    const float* mels  = (const float*)d_in[0];
    const float* means = (const float*)d_in[1];
    const float* stds  = (const float*)d_in[2];
    const float* tv    = (const float*)d_in[3];
    const int* inputs_len = (const int*)d_in[4];
    const int* mel_lens   = (const int*)d_in[5];
    float* out = (float*)d_out;

    float* SE = (float*)d_ws;                        // B*T*N floats
    float* ME = SE + (size_t)NB * NT * NN;           // B*T*N floats
    float* A2 = ME + (size_t)NB * NT * NN;           // B*NTP*N floats
    float* B2 = A2 + (size_t)NB * NTP * NN;
    float* C2 = B2 + (size_t)NB * NTP * NN;

    const int rows = NB * NT * NN;                   // 640000
    emission_kernel<<<dim3(rows / 64), dim3(256), 0, stream>>>(
        mels, means, stds, tv, inputs_len, mel_lens, SE, ME);
    const int cthreads = NB * NTP * NN;              // 318400
    combine_kernel<<<dim3((cthreads + 255) / 256), dim3(256), 0, stream>>>(
        SE, ME, A2, B2, C2);
    scan_kernel<<<dim3(NB), dim3(64), 0, stream>>>(
        SE, ME, A2, B2, C2, tv, inputs_len, mel_lens, out);
}